// Round 10
// baseline (189.714 us; speedup 1.0000x reference)
//
#include <hip/hip_runtime.h>

#define HW 16384   // H*W
#define NH 4
#define HD 16

// ---------------- Kernel 1: QKV projection (LDS-staged x, SGPR weights) ------
// grid: dim3(3, 256, 2); block 256. Outputs pixel-major [((b*4+h)*HW+p)*16+d],
// q pre-scaled by 0.25.
__global__ __launch_bounds__(256) void qkv_kernel(
    const float* __restrict__ x, const float* __restrict__ w,
    const float* __restrict__ bias, float* __restrict__ qT,
    float* __restrict__ kT, float* __restrict__ vT)
{
  __shared__ float xs[64][72];
  int slice = blockIdx.x;
  int p0    = blockIdx.y * 64;
  int b     = blockIdx.z;
  int t     = threadIdx.x;

  {
    int c = t >> 2, f4 = t & 3;
    const float4* src = (const float4*)(x + (size_t)(b * 64 + c) * HW + p0);
    float4* dst = (float4*)(&xs[c][0]);
#pragma unroll
    for (int k2 = 0; k2 < 4; ++k2) dst[f4 * 4 + k2] = src[f4 * 4 + k2];
  }
  __syncthreads();

  int px = t & 63;
  int wv  = __builtin_amdgcn_readfirstlane(t >> 6);
  int o16 = slice * 4 + wv;
  int o0  = o16 * 16;
  int tsel = o16 >> 2;
  int h    = o16 & 3;

  float acc[16];
#pragma unroll
  for (int d = 0; d < 16; ++d) acc[d] = bias[o0 + d];

  for (int c4 = 0; c4 < 16; ++c4) {
    float a0 = xs[c4 * 4 + 0][px];
    float a1 = xs[c4 * 4 + 1][px];
    float a2 = xs[c4 * 4 + 2][px];
    float a3 = xs[c4 * 4 + 3][px];
#pragma unroll
    for (int d = 0; d < 16; ++d) {
      const float* wr = w + (o0 + d) * 64 + c4 * 4;
      acc[d] = fmaf(wr[0], a0, acc[d]);
      acc[d] = fmaf(wr[1], a1, acc[d]);
      acc[d] = fmaf(wr[2], a2, acc[d]);
      acc[d] = fmaf(wr[3], a3, acc[d]);
    }
  }
  if (tsel == 0) {
#pragma unroll
    for (int d = 0; d < 16; ++d) acc[d] *= 0.25f;
  }
  float* dst = (tsel == 0) ? qT : ((tsel == 1) ? kT : vT);
  float4* dp = (float4*)(dst + ((size_t)(b * NH + h) * HW + p0 + px) * HD);
  dp[0] = make_float4(acc[0], acc[1], acc[2], acc[3]);
  dp[1] = make_float4(acc[4], acc[5], acc[6], acc[7]);
  dp[2] = make_float4(acc[8], acc[9], acc[10], acc[11]);
  dp[3] = make_float4(acc[12], acc[13], acc[14], acc[15]);
}

// ---------------- Kernel 2: attention, 4-way key-slice split -----------------
// grid: dim3(256, 4, 2) = (64-px strip, head, batch); block 256 = 64px x 4
// slices. 2048 blocks x 4 waves = 8192 waves = 32 waves/CU supply (4x the old
// one-thread-per-(px,head) cap of 8). Slice = wave-uniform (t>>6); slice s
// owns keys [12s, 12s+12) (+ key 48 on s=0). Two-level softmax and PV-partial
// reduction through LDS.

#define DOT16Q(LGI, KPTR, RBV)                                          \
  { const float4* kp = (const float4*)(KPTR);                           \
    float4 k0 = kp[0], k1 = kp[1], k2 = kp[2], k3 = kp[3];              \
    float dd = (RBV);                                                   \
    dd = fmaf(qd[0], k0.x, dd);  dd = fmaf(qd[1], k0.y, dd);            \
    dd = fmaf(qd[2], k0.z, dd);  dd = fmaf(qd[3], k0.w, dd);            \
    dd = fmaf(qd[4], k1.x, dd);  dd = fmaf(qd[5], k1.y, dd);            \
    dd = fmaf(qd[6], k1.z, dd);  dd = fmaf(qd[7], k1.w, dd);            \
    dd = fmaf(qd[8], k2.x, dd);  dd = fmaf(qd[9], k2.y, dd);            \
    dd = fmaf(qd[10], k2.z, dd); dd = fmaf(qd[11], k2.w, dd);           \
    dd = fmaf(qd[12], k3.x, dd); dd = fmaf(qd[13], k3.y, dd);           \
    dd = fmaf(qd[14], k3.z, dd); dd = fmaf(qd[15], k3.w, dd);           \
    lg[LGI] = dd; }

#define PVACC(LGI, VPTR)                                                \
  { const float4* vp = (const float4*)(VPTR);                           \
    float4 v0 = vp[0], v1 = vp[1], v2 = vp[2], v3 = vp[3];              \
    float p = lg[LGI];                                                  \
    o[0] = fmaf(p, v0.x, o[0]);   o[1] = fmaf(p, v0.y, o[1]);           \
    o[2] = fmaf(p, v0.z, o[2]);   o[3] = fmaf(p, v0.w, o[3]);           \
    o[4] = fmaf(p, v1.x, o[4]);   o[5] = fmaf(p, v1.y, o[5]);           \
    o[6] = fmaf(p, v1.z, o[6]);   o[7] = fmaf(p, v1.w, o[7]);           \
    o[8] = fmaf(p, v2.x, o[8]);   o[9] = fmaf(p, v2.y, o[9]);           \
    o[10] = fmaf(p, v2.z, o[10]); o[11] = fmaf(p, v2.w, o[11]);         \
    o[12] = fmaf(p, v3.x, o[12]); o[13] = fmaf(p, v3.y, o[13]);         \
    o[14] = fmaf(p, v3.z, o[14]); o[15] = fmaf(p, v3.w, o[15]); }

__global__ __launch_bounds__(256, 5) void attn_kernel(
    const float* __restrict__ qT, const float* __restrict__ kT,
    const float* __restrict__ vT, const float* __restrict__ rb,
    float* __restrict__ attO)
{
  __shared__ float rbl[169];
  __shared__ float lsm[64][5];        // per-px per-slice max (pad->bank-free)
  __shared__ float lss[64][5];        // per-px per-slice expsum
  __shared__ float obuf[4][64][17];   // PV partials (stride 17 -> bank-free)

  int t  = threadIdx.x;
  int px = t & 63;
  int s  = __builtin_amdgcn_readfirstlane(t >> 6);   // wave-uniform slice
  int h  = blockIdx.y;
  int b  = blockIdx.z;
  int n  = blockIdx.x * 64 + px;
  int y  = n >> 7, xc = n & 127;
  int sy = y - 3;  sy = sy < 0 ? 0 : (sy > 121 ? 121 : sy);
  int sx = xc - 3; sx = sx < 0 ? 0 : (sx > 121 ? 121 : sx);
  int ih = y - sy, iw = xc - sx;

  if (t < 169) rbl[t] = rb[t * NH + h];
  __syncthreads();

  size_t base = (size_t)(b * NH + h) * HW;

  float qd[16];
  {
    const float4* qp = (const float4*)(qT + (base + n) * HD);
    float4 a = qp[0], b4 = qp[1], c = qp[2], dv = qp[3];
    qd[0] = a.x;  qd[1] = a.y;  qd[2] = a.z;  qd[3] = a.w;
    qd[4] = b4.x; qd[5] = b4.y; qd[6] = b4.z; qd[7] = b4.w;
    qd[8] = c.x;  qd[9] = c.y;  qd[10] = c.z; qd[11] = c.w;
    qd[12] = dv.x; qd[13] = dv.y; qd[14] = dv.z; qd[15] = dv.w;
  }

  const float* kwin = kT + (base + (size_t)sy * 128 + sx) * HD;
  const float* vwin = vT + (base + (size_t)sy * 128 + sx) * HD;
  int kbase = s * 12;

  // ---- QK^T over this slice's keys ----
  float lg[13];
#pragma unroll
  for (int kk = 0; kk < 12; ++kk) {
    int key = kbase + kk;            // wave-uniform
    int ro  = key / 7;
    int j   = key - ro * 7;
    DOT16Q(kk, kwin + ((size_t)ro * 128 + j) * HD, rbl[(ih + ro) * 13 + iw + j]);
  }
  if (s == 0) {
    DOT16Q(12, kwin + ((size_t)6 * 128 + 6) * HD, rbl[(ih + 6) * 13 + iw + 6]);
  } else {
    lg[12] = -1e30f;                 // dummy: exp -> 0
  }

  // ---- slice-local softmax ----
  float m_s = lg[0];
#pragma unroll
  for (int k = 1; k < 13; ++k) m_s = fmaxf(m_s, lg[k]);
  float s_s = 0.f;
#pragma unroll
  for (int k = 0; k < 13; ++k) { lg[k] = __expf(lg[k] - m_s); s_s += lg[k]; }
  lsm[px][s] = m_s;
  lss[px][s] = s_s;
  __syncthreads();

  // ---- combine slice stats ----
  float m0 = lsm[px][0], m1 = lsm[px][1], m2 = lsm[px][2], m3 = lsm[px][3];
  float mg = fmaxf(fmaxf(m0, m1), fmaxf(m2, m3));
  float tot = lss[px][0] * __expf(m0 - mg) + lss[px][1] * __expf(m1 - mg)
            + lss[px][2] * __expf(m2 - mg) + lss[px][3] * __expf(m3 - mg);
  float fac = __expf(m_s - mg) / tot;

  // ---- PV over this slice's keys ----
  float o[16];
#pragma unroll
  for (int d = 0; d < 16; ++d) o[d] = 0.f;
#pragma unroll
  for (int kk = 0; kk < 12; ++kk) {
    int key = kbase + kk;
    int ro  = key / 7;
    int j   = key - ro * 7;
    PVACC(kk, vwin + ((size_t)ro * 128 + j) * HD);
  }
  if (s == 0) { PVACC(12, vwin + ((size_t)6 * 128 + 6) * HD); }

#pragma unroll
  for (int d = 0; d < 16; ++d) obuf[s][px][d] = o[d] * fac;
  __syncthreads();

  // ---- reduce partials: thread (px,s) outputs channels d = 4s..4s+3 ----
  float* ob = attO + (size_t)(b * 64 + h * 16 + s * 4) * HW + n;
#pragma unroll
  for (int i = 0; i < 4; ++i) {
    int d = s * 4 + i;
    float v = obuf[0][px][d] + obuf[1][px][d] + obuf[2][px][d] + obuf[3][px][d];
    ob[(size_t)i * HW] = v;
  }
}

// ---------------- Kernel 3: output projection (in-place over d_out) ----------
__global__ __launch_bounds__(256) void proj_kernel(
    const float* __restrict__ pw, const float* __restrict__ pb,
    float* __restrict__ out)
{
  __shared__ float as[64][72];
  int p0 = blockIdx.x * 64;
  int b  = blockIdx.y;
  int t  = threadIdx.x;

  {
    int c = t >> 2, f4 = t & 3;
    const float4* src = (const float4*)(out + (size_t)(b * 64 + c) * HW + p0);
    float4* dst = (float4*)(&as[c][0]);
#pragma unroll
    for (int k2 = 0; k2 < 4; ++k2) dst[f4 * 4 + k2] = src[f4 * 4 + k2];
  }
  __syncthreads();

  int px = t & 63;
  int og = __builtin_amdgcn_readfirstlane(t >> 6);
  float acc[16];
#pragma unroll
  for (int oo = 0; oo < 16; ++oo) acc[oo] = pb[og * 16 + oo];

  for (int c4 = 0; c4 < 16; ++c4) {
    float a0 = as[c4 * 4 + 0][px];
    float a1 = as[c4 * 4 + 1][px];
    float a2 = as[c4 * 4 + 2][px];
    float a3 = as[c4 * 4 + 3][px];
#pragma unroll
    for (int oo = 0; oo < 16; ++oo) {
      const float* wr = pw + (og * 16 + oo) * 64 + c4 * 4;
      acc[oo] = fmaf(wr[0], a0, acc[oo]);
      acc[oo] = fmaf(wr[1], a1, acc[oo]);
      acc[oo] = fmaf(wr[2], a2, acc[oo]);
      acc[oo] = fmaf(wr[3], a3, acc[oo]);
    }
  }
#pragma unroll
  for (int oo = 0; oo < 16; ++oo)
    out[((size_t)b * 64 + og * 16 + oo) * HW + p0 + px] = acc[oo];
}

extern "C" void kernel_launch(void* const* d_in, const int* in_sizes, int n_in,
                              void* d_out, int out_size, void* d_ws, size_t ws_size,
                              hipStream_t stream) {
  const float* x      = (const float*)d_in[0];
  const float* qkv_w  = (const float*)d_in[1];
  const float* qkv_b  = (const float*)d_in[2];
  const float* proj_w = (const float*)d_in[3];
  const float* proj_b = (const float*)d_in[4];
  const float* rb     = (const float*)d_in[5];
  float* out = (float*)d_out;

  const size_t TSZ = (size_t)2 * NH * HW * HD;   // 2,097,152 floats each
  float* qT = (float*)d_ws;
  float* kT = qT + TSZ;
  float* vT = kT + TSZ;

  qkv_kernel<<<dim3(3, 256, 2), 256, 0, stream>>>(x, qkv_w, qkv_b, qT, kT, vT);
  attn_kernel<<<dim3(256, NH, 2), 256, 0, stream>>>(qT, kT, vT, rb, out);
  proj_kernel<<<dim3(256, 2), 256, 0, stream>>>(proj_w, proj_b, out);
}

// Round 11
// 72.782 us; speedup vs baseline: 2.6066x; 2.6066x over previous
//
#include <hip/hip_runtime.h>

#define HW 16384   // H*W
#define NH 4
#define HD 16

// ---------------- Kernel 1: QKV projection (LDS-staged x, SGPR weights) ------
// grid: dim3(3, 256, 2); block 256. Outputs pixel-major [((b*4+h)*HW+p)*16+d],
// q pre-scaled by 0.25.
__global__ __launch_bounds__(256) void qkv_kernel(
    const float* __restrict__ x, const float* __restrict__ w,
    const float* __restrict__ bias, float* __restrict__ qT,
    float* __restrict__ kT, float* __restrict__ vT)
{
  __shared__ float xs[64][72];
  int slice = blockIdx.x;
  int p0    = blockIdx.y * 64;
  int b     = blockIdx.z;
  int t     = threadIdx.x;

  {
    int c = t >> 2, f4 = t & 3;
    const float4* src = (const float4*)(x + (size_t)(b * 64 + c) * HW + p0);
    float4* dst = (float4*)(&xs[c][0]);
#pragma unroll
    for (int k2 = 0; k2 < 4; ++k2) dst[f4 * 4 + k2] = src[f4 * 4 + k2];
  }
  __syncthreads();

  int px = t & 63;
  int wv  = __builtin_amdgcn_readfirstlane(t >> 6);
  int o16 = slice * 4 + wv;
  int o0  = o16 * 16;
  int tsel = o16 >> 2;
  int h    = o16 & 3;

  float acc[16];
#pragma unroll
  for (int d = 0; d < 16; ++d) acc[d] = bias[o0 + d];

  for (int c4 = 0; c4 < 16; ++c4) {
    float a0 = xs[c4 * 4 + 0][px];
    float a1 = xs[c4 * 4 + 1][px];
    float a2 = xs[c4 * 4 + 2][px];
    float a3 = xs[c4 * 4 + 3][px];
#pragma unroll
    for (int d = 0; d < 16; ++d) {
      const float* wr = w + (o0 + d) * 64 + c4 * 4;
      acc[d] = fmaf(wr[0], a0, acc[d]);
      acc[d] = fmaf(wr[1], a1, acc[d]);
      acc[d] = fmaf(wr[2], a2, acc[d]);
      acc[d] = fmaf(wr[3], a3, acc[d]);
    }
  }
  if (tsel == 0) {
#pragma unroll
    for (int d = 0; d < 16; ++d) acc[d] *= 0.25f;
  }
  float* dst = (tsel == 0) ? qT : ((tsel == 1) ? kT : vT);
  float4* dp = (float4*)(dst + ((size_t)(b * NH + h) * HW + p0 + px) * HD);
  dp[0] = make_float4(acc[0], acc[1], acc[2], acc[3]);
  dp[1] = make_float4(acc[4], acc[5], acc[6], acc[7]);
  dp[2] = make_float4(acc[8], acc[9], acc[10], acc[11]);
  dp[3] = make_float4(acc[12], acc[13], acc[14], acc[15]);
}

// ---------------- Kernel 2: attention, lane = (pixel, d-quad) ----------------
// grid: dim3(256, 4, 2) = (64-px strip, head, batch); block 256 (4 waves).
// Wave = 16 px x 4 d-quads. Per key: ONE coalesced float4 load per wave
// (64 lanes = 16 consecutive px x 64B K-vector = 1KB contiguous, 16 lines —
// vs 64 lines/inst in the px-per-lane layout). 4-wide partial dot per lane,
// full dot via 2x quad shfl_xor (DPP, no LDS). Softmax redundant across the
// 4 d-lanes (free). PV output quad stays lane-local. No barriers after rbl.
// 8192 waves = 32 waves/CU supply; ~75 VGPR.
__global__ __launch_bounds__(256, 4) void attn_kernel(
    const float* __restrict__ qT, const float* __restrict__ kT,
    const float* __restrict__ vT, const float* __restrict__ rb,
    float* __restrict__ attO)
{
  __shared__ float rbl[169];

  int t  = threadIdx.x;
  int g  = t & 3;                  // d-quad: channels 4g..4g+3 (PER-LANE)
  int pl = t >> 2;                 // local pixel 0..63
  int h  = blockIdx.y;
  int b  = blockIdx.z;
  int n  = blockIdx.x * 64 + pl;
  int y  = n >> 7, xc = n & 127;
  int sy = y - 3;  sy = sy < 0 ? 0 : (sy > 121 ? 121 : sy);
  int sx = xc - 3; sx = sx < 0 ? 0 : (sx > 121 ? 121 : sx);
  int ih = y - sy, iw = xc - sx;

  if (t < 169) rbl[t] = rb[t * NH + h];
  __syncthreads();

  size_t base = (size_t)(b * NH + h) * HW;

  // this lane's quarter of q
  float4 qd = *(const float4*)(qT + (base + n) * HD + 4 * g);

  const float* kwin = kT + (base + (size_t)sy * 128 + sx) * HD + 4 * g;
  const float* vwin = vT + (base + (size_t)sy * 128 + sx) * HD + 4 * g;

  // ---- pass 1: QK^T (one coalesced float4 load per wave per key) ----
  float lg[49];
#pragma unroll
  for (int i = 0; i < 7; ++i) {
#pragma unroll
    for (int j = 0; j < 7; ++j) {
      float4 kf = *(const float4*)(kwin + ((size_t)i * 128 + j) * HD);
      float p = qd.x * kf.x;
      p = fmaf(qd.y, kf.y, p);
      p = fmaf(qd.z, kf.z, p);
      p = fmaf(qd.w, kf.w, p);
      p += __shfl_xor(p, 1, 4);    // quad butterfly: all 4 lanes get full dot
      p += __shfl_xor(p, 2, 4);
      lg[i * 7 + j] = p + rbl[(ih + i) * 13 + (iw + j)];
    }
  }

  // ---- softmax (redundant in the 4 d-lanes of each pixel — same wave) ----
  float mx = lg[0];
#pragma unroll
  for (int k = 1; k < 49; ++k) mx = fmaxf(mx, lg[k]);
  float s = 0.f;
#pragma unroll
  for (int k = 0; k < 49; ++k) { lg[k] = __expf(lg[k] - mx); s += lg[k]; }
  float inv = 1.f / s;

  // ---- pass 2: PV (lane-local accumulation of its 4 channels) ----
  float4 o = make_float4(0.f, 0.f, 0.f, 0.f);
#pragma unroll
  for (int i = 0; i < 7; ++i) {
#pragma unroll
    for (int j = 0; j < 7; ++j) {
      float4 vf = *(const float4*)(vwin + ((size_t)i * 128 + j) * HD);
      float p = lg[i * 7 + j];
      o.x = fmaf(p, vf.x, o.x);
      o.y = fmaf(p, vf.y, o.y);
      o.z = fmaf(p, vf.z, o.z);
      o.w = fmaf(p, vf.w, o.w);
    }
  }

  // ---- write channel-major into attO (= d_out, overwritten by proj) ----
  float* ob = attO + (size_t)(b * 64 + h * 16 + 4 * g) * HW + n;
  ob[0]          = o.x * inv;
  ob[(size_t)HW]     = o.y * inv;
  ob[(size_t)2 * HW] = o.z * inv;
  ob[(size_t)3 * HW] = o.w * inv;
}

// ---------------- Kernel 3: output projection (in-place over d_out) ----------
__global__ __launch_bounds__(256) void proj_kernel(
    const float* __restrict__ pw, const float* __restrict__ pb,
    float* __restrict__ out)
{
  __shared__ float as[64][72];
  int p0 = blockIdx.x * 64;
  int b  = blockIdx.y;
  int t  = threadIdx.x;

  {
    int c = t >> 2, f4 = t & 3;
    const float4* src = (const float4*)(out + (size_t)(b * 64 + c) * HW + p0);
    float4* dst = (float4*)(&as[c][0]);
#pragma unroll
    for (int k2 = 0; k2 < 4; ++k2) dst[f4 * 4 + k2] = src[f4 * 4 + k2];
  }
  __syncthreads();

  int px = t & 63;
  int og = __builtin_amdgcn_readfirstlane(t >> 6);
  float acc[16];
#pragma unroll
  for (int oo = 0; oo < 16; ++oo) acc[oo] = pb[og * 16 + oo];

  for (int c4 = 0; c4 < 16; ++c4) {
    float a0 = as[c4 * 4 + 0][px];
    float a1 = as[c4 * 4 + 1][px];
    float a2 = as[c4 * 4 + 2][px];
    float a3 = as[c4 * 4 + 3][px];
#pragma unroll
    for (int oo = 0; oo < 16; ++oo) {
      const float* wr = pw + (og * 16 + oo) * 64 + c4 * 4;
      acc[oo] = fmaf(wr[0], a0, acc[oo]);
      acc[oo] = fmaf(wr[1], a1, acc[oo]);
      acc[oo] = fmaf(wr[2], a2, acc[oo]);
      acc[oo] = fmaf(wr[3], a3, acc[oo]);
    }
  }
#pragma unroll
  for (int oo = 0; oo < 16; ++oo)
    out[((size_t)b * 64 + og * 16 + oo) * HW + p0 + px] = acc[oo];
}

extern "C" void kernel_launch(void* const* d_in, const int* in_sizes, int n_in,
                              void* d_out, int out_size, void* d_ws, size_t ws_size,
                              hipStream_t stream) {
  const float* x      = (const float*)d_in[0];
  const float* qkv_w  = (const float*)d_in[1];
  const float* qkv_b  = (const float*)d_in[2];
  const float* proj_w = (const float*)d_in[3];
  const float* proj_b = (const float*)d_in[4];
  const float* rb     = (const float*)d_in[5];
  float* out = (float*)d_out;

  const size_t TSZ = (size_t)2 * NH * HW * HD;   // 2,097,152 floats each
  float* qT = (float*)d_ws;
  float* kT = qT + TSZ;
  float* vT = kT + TSZ;

  qkv_kernel<<<dim3(3, 256, 2), 256, 0, stream>>>(x, qkv_w, qkv_b, qT, kT, vT);
  attn_kernel<<<dim3(256, NH, 2), 256, 0, stream>>>(qT, kT, vT, rb, out);
  proj_kernel<<<dim3(256, 2), 256, 0, stream>>>(proj_w, proj_b, out);
}